// Round 3
// baseline (661.206 us; speedup 1.0000x reference)
//
#include <hip/hip_runtime.h>
#include <hip/hip_bf16.h>

#define NROW 8192
#define DIM 256

typedef short bf16x8 __attribute__((ext_vector_type(8)));
typedef float f32x4 __attribute__((ext_vector_type(4)));

__device__ __forceinline__ short f2bf(float x) {
    return __builtin_bit_cast(short, __float2bfloat16(x));
}

__device__ __forceinline__ void gload_lds16(const void* g, void* l) {
    __builtin_amdgcn_global_load_lds(
        (const __attribute__((address_space(1))) unsigned int*)g,
        (__attribute__((address_space(3))) unsigned int*)l, 16, 0, 0);
}

// ---------------------------------------------------------------------------
// k1: Wh = h @ W (fp32 accum). Epilogue: f[j] += Wh[j][:] . a  (atomic partial
// per 64-col block) and whbT in K-TILED layout for k4's global_load_lds:
//   whbT[((k>>6)*256 + n)*64 + (k&63)] = bf16(Wh[k][n])
// grid (128, 4), block 256
// ---------------------------------------------------------------------------
__global__ __launch_bounds__(256) void k1_whgemm(
    const float* __restrict__ h, const float* __restrict__ W,
    const float* __restrict__ a, short* __restrict__ whbT,
    float* __restrict__ f)
{
    __shared__ float hs[64][65];
    __shared__ float wsm[64][65];
    const int tid = threadIdx.x;
    const int tx = tid & 15, ty = tid >> 4;
    const int i0 = blockIdx.x * 64;
    const int n0 = blockIdx.y * 64;

    float acc[4][4];
#pragma unroll
    for (int u = 0; u < 4; ++u)
#pragma unroll
        for (int v = 0; v < 4; ++v) acc[u][v] = 0.f;

    for (int kb = 0; kb < DIM; kb += 64) {
#pragma unroll
        for (int rr = 0; rr < 4; ++rr) {
            int row = rr * 16 + ty;
            *(float4*)&hs[row][tx * 4] =
                *(const float4*)&h[(size_t)(i0 + row) * DIM + kb + tx * 4];
            *(float4*)&wsm[row][tx * 4] =
                *(const float4*)&W[(size_t)(kb + row) * DIM + n0 + tx * 4];
        }
        __syncthreads();
#pragma unroll 8
        for (int kk = 0; kk < 64; ++kk) {
            float av[4], bv[4];
#pragma unroll
            for (int u = 0; u < 4; ++u) av[u] = hs[ty * 4 + u][kk];
#pragma unroll
            for (int v = 0; v < 4; ++v) bv[v] = wsm[kk][tx * 4 + v];
#pragma unroll
            for (int u = 0; u < 4; ++u)
#pragma unroll
                for (int v = 0; v < 4; ++v) acc[u][v] += av[u] * bv[v];
        }
        __syncthreads();
    }

#pragma unroll
    for (int u = 0; u < 4; ++u)
#pragma unroll
        for (int v = 0; v < 4; ++v) hs[ty * 4 + u][tx * 4 + v] = acc[u][v];
    __syncthreads();

    {
        int r = tid >> 2, q = tid & 3;
        float s = 0.f;
#pragma unroll
        for (int c = 0; c < 16; ++c) s += hs[r][q * 16 + c] * a[n0 + q * 16 + c];
        s += __shfl_xor(s, 1);
        s += __shfl_xor(s, 2);
        if (q == 0) atomicAdd(&f[i0 + r], s);
    }

    {
        int n = tid >> 2, q = tid & 3;
        union { short s[16]; int4 i4[2]; } pk;
#pragma unroll
        for (int b = 0; b < 4; ++b)
#pragma unroll
            for (int c = 0; c < 4; ++c)
                pk.s[b * 4 + c] = f2bf(hs[q * 16 + b * 4 + c][n]);
        size_t base = ((size_t)(i0 >> 6) * 256 + n0 + n) * 64 + q * 16;
        *(int4*)&whbT[base] = pk.i4[0];
        *(int4*)&whbT[base + 8] = pk.i4[1];
    }
}

// ---------------------------------------------------------------------------
// k3c: one block per row i. Pure stream: read adj (int4), t = exp(lrelu)
// held in regs, one block reduction for l, scale, float4 alpha writes.
// grid 8192, block 256
// ---------------------------------------------------------------------------
__global__ __launch_bounds__(256) void k3c_alpha(
    const int* __restrict__ adj, const float* __restrict__ f,
    float* __restrict__ alpha)
{
    const int i = blockIdx.x;
    const int tid = threadIdx.x;
    const float fi = f[i];
    const int* row = adj + (size_t)i * NROW;

    float4 tv[8];
    float sum = 0.f;
#pragma unroll
    for (int it = 0; it < 8; ++it) {
        const int j = it * 1024 + tid * 4;
        int4 av = *(const int4*)&row[j];
        float4 fv = *(const float4*)&f[j];
        float x0 = fi + fv.x, x1 = fi + fv.y, x2 = fi + fv.z, x3 = fi + fv.w;
        float4 t;
        t.x = av.x > 0 ? __expf(fmaxf(x0, 0.2f * x0)) : 0.f;
        t.y = av.y > 0 ? __expf(fmaxf(x1, 0.2f * x1)) : 0.f;
        t.z = av.z > 0 ? __expf(fmaxf(x2, 0.2f * x2)) : 0.f;
        t.w = av.w > 0 ? __expf(fmaxf(x3, 0.2f * x3)) : 0.f;
        tv[it] = t;
        sum += t.x + t.y + t.z + t.w;
    }

#pragma unroll
    for (int off = 32; off > 0; off >>= 1) sum += __shfl_xor(sum, off);
    __shared__ float red[4];
    if ((tid & 63) == 0) red[tid >> 6] = sum;
    __syncthreads();
    const float inv = 1.f / (red[0] + red[1] + red[2] + red[3]);

    float* arow = alpha + (size_t)i * NROW;
#pragma unroll
    for (int it = 0; it < 8; ++it) {
        float4 t = tv[it];
        float4 o = {t.x * inv, t.y * inv, t.z * inv, t.w * inv};
        *(float4*)&arow[it * 1024 + tid * 4] = o;
    }
}

// ---------------------------------------------------------------------------
// k4f: out0 = elu(alpha @ Wh), full-K per block, no atomics.
// Depth-3 counted-vmcnt pipeline, 4 x 32 KB LDS buffers. Per iter:
//   vmcnt(16) [tile kt done, 16 ops of kt+1/kt+2 stay in flight]
//   sched_barrier(0)   <- rule 18: nothing reading tile kt hoists above wait
//   s_barrier          <- also makes buf (kt-1)&3 write-safe
//   sched_barrier(0)
//   STAGE/ALOAD(kt+3) into buf (kt+3)&3 == (kt-1)&3
//   CONSUME(kt): converts + ds_read + MFMA (setprio 1 around MFMA cluster)
// Stage AFTER the barrier => one barrier/iter protects reads AND writes.
// Block = 32 rows x 256 cols, 512 threads = 8 waves. elu fused. grid 256.
// ---------------------------------------------------------------------------
__global__ __launch_bounds__(512) void k4f_gemm(
    const float* __restrict__ alpha, const short* __restrict__ whbT,
    float* __restrict__ out0)
{
    __shared__ __align__(16) short Bs[4][16384];   // 4 x 32 KB = 128 KB

    const int tid = threadIdx.x;
    const int wave = tid >> 6;
    const int lane = tid & 63;
    const int lo = lane & 15;
    const int quad = lane >> 4;
    const int q8 = quad * 8;
    const int rg = wave & 1;          // row group: 16 rows
    const int cg = wave >> 1;         // col group: 64 cols (4 nt)
    const int i0 = blockIdx.x * 32;

    const float* aptr = alpha + (size_t)(i0 + rg * 16 + lo) * NROW + q8;

    // staging: linear LDS dest (gload_lds), source chunk XOR'd with row&7
    const int srow = lane >> 3;
    const int swz = ((lane & 7) ^ srow) * 8;

    // fragment read offsets (shorts), same XOR on read side
    const int bx0 = (quad ^ (lo & 7)) * 8;
    const int bx1 = ((4 + quad) ^ (lo & 7)) * 8;
    int off0[4], off1[4];
#pragma unroll
    for (int nt = 0; nt < 4; ++nt) {
        int rb = (cg * 64 + nt * 16 + lo) * 64;
        off0[nt] = rb + bx0;
        off1[nt] = rb + bx1;
    }

    f32x4 acc[4] = {};
    f32x4 aA[4], aB[4], aC[4], aD[4];   // A prefetch sets, static idx only

#define STAGE(buf, kt)                                                        \
    {                                                                         \
        const short* gtile = whbT + (size_t)(kt) * 16384;                     \
        _Pragma("unroll")                                                     \
        for (int s = 0; s < 4; ++s)                                           \
            gload_lds16(gtile + ((wave * 4 + s) * 8 + srow) * 64 + swz,       \
                        &Bs[buf][(wave * 4 + s) * 512]);                      \
    }

#define ALOAD(set, kt)                                                        \
    {                                                                         \
        const float* ap = aptr + (size_t)(kt) * 64;                           \
        asm volatile("global_load_dwordx4 %0, %4, off\n\t"                    \
                     "global_load_dwordx4 %1, %4, off offset:16\n\t"          \
                     "global_load_dwordx4 %2, %4, off offset:128\n\t"         \
                     "global_load_dwordx4 %3, %4, off offset:144"             \
                     : "=&v"(aA[set]), "=&v"(aB[set]),                        \
                       "=&v"(aC[set]), "=&v"(aD[set])                         \
                     : "v"(ap));                                              \
    }

#define CONSUME(c)                                                            \
    {                                                                         \
        bf16x8 af0, af1;                                                      \
        af0[0] = f2bf(aA[c][0]); af0[1] = f2bf(aA[c][1]);                     \
        af0[2] = f2bf(aA[c][2]); af0[3] = f2bf(aA[c][3]);                     \
        af0[4] = f2bf(aB[c][0]); af0[5] = f2bf(aB[c][1]);                     \
        af0[6] = f2bf(aB[c][2]); af0[7] = f2bf(aB[c][3]);                     \
        af1[0] = f2bf(aC[c][0]); af1[1] = f2bf(aC[c][1]);                     \
        af1[2] = f2bf(aC[c][2]); af1[3] = f2bf(aC[c][3]);                     \
        af1[4] = f2bf(aD[c][0]); af1[5] = f2bf(aD[c][1]);                     \
        af1[6] = f2bf(aD[c][2]); af1[7] = f2bf(aD[c][3]);                     \
        __builtin_amdgcn_s_setprio(1);                                        \
        _Pragma("unroll")                                                     \
        for (int nt = 0; nt < 4; ++nt) {                                      \
            bf16x8 b0 = *(const bf16x8*)&Bs[c][off0[nt]];                     \
            acc[nt] = __builtin_amdgcn_mfma_f32_16x16x32_bf16(af0, b0,        \
                                                          acc[nt], 0, 0, 0);  \
            bf16x8 b1 = *(const bf16x8*)&Bs[c][off1[nt]];                     \
            acc[nt] = __builtin_amdgcn_mfma_f32_16x16x32_bf16(af1, b1,        \
                                                          acc[nt], 0, 0, 0);  \
        }                                                                     \
        __builtin_amdgcn_s_setprio(0);                                        \
    }

#define KSTEP(kt, c, DO, N)                                                   \
    {                                                                         \
        asm volatile("s_waitcnt vmcnt(" #N ")" ::: "memory");                 \
        __builtin_amdgcn_sched_barrier(0);                                    \
        __builtin_amdgcn_s_barrier();                                         \
        __builtin_amdgcn_sched_barrier(0);                                    \
        if (DO) {                                                             \
            STAGE(((c) + 3) & 3, (kt) + 3);                                   \
            ALOAD(((c) + 3) & 3, (kt) + 3);                                   \
        }                                                                     \
        CONSUME(c)                                                            \
    }

    // prologue: issue tiles 0,1,2 (depth 3) = 24 vmem ops per wave
    STAGE(0, 0); ALOAD(0, 0);
    STAGE(1, 1); ALOAD(1, 1);
    STAGE(2, 2); ALOAD(2, 2);

#pragma unroll 1
    for (int base = 0; base < 124; base += 4) {
        KSTEP(base + 0, 0, true, 16)
        KSTEP(base + 1, 1, true, 16)
        KSTEP(base + 2, 2, true, 16)
        KSTEP(base + 3, 3, true, 16)
    }
    KSTEP(124, 0, true, 16)     // stages tile 127 into buf 3
    KSTEP(125, 1, false, 16)    // outstanding 24 -> drain tile 125
    KSTEP(126, 2, false, 8)     // outstanding 16 -> drain tile 126
    KSTEP(127, 3, false, 0)     // drain all

#undef STAGE
#undef ALOAD
#undef CONSUME
#undef KSTEP

    // C/D layout: col = lane&15, row = quad*4 + reg. elu fused.
    const int ccb = cg * 64 + lo;
#pragma unroll
    for (int nt = 0; nt < 4; ++nt) {
#pragma unroll
        for (int c = 0; c < 4; ++c) {
            const int rr = i0 + rg * 16 + quad * 4 + c;
            float v = acc[nt][c];
            v = v > 0.f ? v : __expf(v) - 1.f;
            out0[(size_t)rr * DIM + ccb + nt * 16] = v;
        }
    }
}

extern "C" void kernel_launch(void* const* d_in, const int* in_sizes, int n_in,
                              void* d_out, int out_size, void* d_ws, size_t ws_size,
                              hipStream_t stream) {
    const float* h = (const float*)d_in[0];
    const int* adj = (const int*)d_in[1];
    const float* W = (const float*)d_in[2];
    const float* a = (const float*)d_in[3];
    float* out0 = (float*)d_out;                        // elu(h_prime) [8192,256]
    float* alpha = out0 + (size_t)NROW * DIM;           // alpha [8192,8192]

    char* ws = (char*)d_ws;
    float* f = (float*)ws;                              // 32 KB
    short* whbT = (short*)(ws + 32768);                 // 4 MB bf16, K-tiled

    hipMemsetAsync(f, 0, NROW * sizeof(float), stream);
    k1_whgemm<<<dim3(NROW / 64, DIM / 64), 256, 0, stream>>>(h, W, a, whbT, f);
    k3c_alpha<<<dim3(NROW), 256, 0, stream>>>(adj, f, alpha);
    k4f_gemm<<<dim3(NROW / 32), 512, 0, stream>>>(alpha, whbT, out0);
}

// Round 4
// 638.835 us; speedup vs baseline: 1.0350x; 1.0350x over previous
//
#include <hip/hip_runtime.h>
#include <hip/hip_bf16.h>

#define NROW 8192
#define DIM 256

typedef short bf16x8 __attribute__((ext_vector_type(8)));
typedef float f32x4 __attribute__((ext_vector_type(4)));

__device__ __forceinline__ short f2bf(float x) {
    return __builtin_bit_cast(short, __float2bfloat16(x));
}

__device__ __forceinline__ void gload_lds16(const void* g, void* l) {
    __builtin_amdgcn_global_load_lds(
        (const __attribute__((address_space(1))) unsigned int*)g,
        (__attribute__((address_space(3))) unsigned int*)l, 16, 0, 0);
}

// ---------------------------------------------------------------------------
// k1: Wh = h @ W (fp32 accum). Epilogue: f[j] += Wh[j][:] . a  (atomic partial
// per 64-col block) and whbT in K-TILED layout for k4's global_load_lds:
//   whbT[((k>>6)*256 + n)*64 + (k&63)] = bf16(Wh[k][n])
// grid (128, 4), block 256
// ---------------------------------------------------------------------------
__global__ __launch_bounds__(256) void k1_whgemm(
    const float* __restrict__ h, const float* __restrict__ W,
    const float* __restrict__ a, short* __restrict__ whbT,
    float* __restrict__ f)
{
    __shared__ float hs[64][65];
    __shared__ float wsm[64][65];
    const int tid = threadIdx.x;
    const int tx = tid & 15, ty = tid >> 4;
    const int i0 = blockIdx.x * 64;
    const int n0 = blockIdx.y * 64;

    float acc[4][4];
#pragma unroll
    for (int u = 0; u < 4; ++u)
#pragma unroll
        for (int v = 0; v < 4; ++v) acc[u][v] = 0.f;

    for (int kb = 0; kb < DIM; kb += 64) {
#pragma unroll
        for (int rr = 0; rr < 4; ++rr) {
            int row = rr * 16 + ty;
            *(float4*)&hs[row][tx * 4] =
                *(const float4*)&h[(size_t)(i0 + row) * DIM + kb + tx * 4];
            *(float4*)&wsm[row][tx * 4] =
                *(const float4*)&W[(size_t)(kb + row) * DIM + n0 + tx * 4];
        }
        __syncthreads();
#pragma unroll 8
        for (int kk = 0; kk < 64; ++kk) {
            float av[4], bv[4];
#pragma unroll
            for (int u = 0; u < 4; ++u) av[u] = hs[ty * 4 + u][kk];
#pragma unroll
            for (int v = 0; v < 4; ++v) bv[v] = wsm[kk][tx * 4 + v];
#pragma unroll
            for (int u = 0; u < 4; ++u)
#pragma unroll
                for (int v = 0; v < 4; ++v) acc[u][v] += av[u] * bv[v];
        }
        __syncthreads();
    }

#pragma unroll
    for (int u = 0; u < 4; ++u)
#pragma unroll
        for (int v = 0; v < 4; ++v) hs[ty * 4 + u][tx * 4 + v] = acc[u][v];
    __syncthreads();

    {
        int r = tid >> 2, q = tid & 3;
        float s = 0.f;
#pragma unroll
        for (int c = 0; c < 16; ++c) s += hs[r][q * 16 + c] * a[n0 + q * 16 + c];
        s += __shfl_xor(s, 1);
        s += __shfl_xor(s, 2);
        if (q == 0) atomicAdd(&f[i0 + r], s);
    }

    {
        int n = tid >> 2, q = tid & 3;
        union { short s[16]; int4 i4[2]; } pk;
#pragma unroll
        for (int b = 0; b < 4; ++b)
#pragma unroll
            for (int c = 0; c < 4; ++c)
                pk.s[b * 4 + c] = f2bf(hs[q * 16 + b * 4 + c][n]);
        size_t base = ((size_t)(i0 >> 6) * 256 + n0 + n) * 64 + q * 16;
        *(int4*)&whbT[base] = pk.i4[0];
        *(int4*)&whbT[base + 8] = pk.i4[1];
    }
}

// ---------------------------------------------------------------------------
// k3d: one block per row i. MLP-restructured: ALL 16 loads (8 int4 adj +
// 8 float4 f) issued as one batch before any exp work, so a wave keeps
// 16 independent vmem ops in flight instead of serializing load->exp->load.
// exp results overwrite fv (keeps VGPR ~80, ~5 waves/SIMD). Math identical
// to verified k3c. grid 8192, block 256
// ---------------------------------------------------------------------------
__global__ __launch_bounds__(256) void k3d_alpha(
    const int* __restrict__ adj, const float* __restrict__ f,
    float* __restrict__ alpha)
{
    const int i = blockIdx.x;
    const int tid = threadIdx.x;
    const float fi = f[i];
    const int* row = adj + (size_t)i * NROW;

    int4 av[8];
    float4 fv[8];
    // burst-issue: 16 independent loads per lane, no VALU between them
#pragma unroll
    for (int it = 0; it < 8; ++it)
        av[it] = *(const int4*)&row[it * 1024 + tid * 4];
#pragma unroll
    for (int it = 0; it < 8; ++it)
        fv[it] = *(const float4*)&f[it * 1024 + tid * 4];

    float sum = 0.f;
#pragma unroll
    for (int it = 0; it < 8; ++it) {
        float x0 = fi + fv[it].x, x1 = fi + fv[it].y;
        float x2 = fi + fv[it].z, x3 = fi + fv[it].w;
        float4 t;
        t.x = av[it].x > 0 ? __expf(fmaxf(x0, 0.2f * x0)) : 0.f;
        t.y = av[it].y > 0 ? __expf(fmaxf(x1, 0.2f * x1)) : 0.f;
        t.z = av[it].z > 0 ? __expf(fmaxf(x2, 0.2f * x2)) : 0.f;
        t.w = av[it].w > 0 ? __expf(fmaxf(x3, 0.2f * x3)) : 0.f;
        fv[it] = t;                        // reuse regs
        sum += t.x + t.y + t.z + t.w;
    }

#pragma unroll
    for (int off = 32; off > 0; off >>= 1) sum += __shfl_xor(sum, off);
    __shared__ float red[4];
    if ((tid & 63) == 0) red[tid >> 6] = sum;
    __syncthreads();
    const float inv = 1.f / (red[0] + red[1] + red[2] + red[3]);

    float* arow = alpha + (size_t)i * NROW;
#pragma unroll
    for (int it = 0; it < 8; ++it) {
        float4 t = fv[it];
        float4 o = {t.x * inv, t.y * inv, t.z * inv, t.w * inv};
        *(float4*)&arow[it * 1024 + tid * 4] = o;
    }
}

// ---------------------------------------------------------------------------
// k4e: out0 = elu(alpha @ Wh), full-K per block, no atomics.
// Depth-2 counted-vmcnt pipeline (best measured: 185 us). 4 x 32 KB LDS
// buffers; per iter: issue STAGE(kt+2)+ALOAD(kt+2), s_waitcnt vmcnt(16)
// (tile kt done, 16 ops in flight across the raw barrier), sched_barrier
// pins the consume phase. grid 256, block 512. elu fused.
// ---------------------------------------------------------------------------
__global__ __launch_bounds__(512, 2) void k4e_gemm(
    const float* __restrict__ alpha, const short* __restrict__ whbT,
    float* __restrict__ out0)
{
    __shared__ __align__(16) short Bs[4][16384];   // 4 x 32 KB = 128 KB

    const int tid = threadIdx.x;
    const int wave = tid >> 6;
    const int lane = tid & 63;
    const int lo = lane & 15;
    const int quad = lane >> 4;
    const int q8 = quad * 8;
    const int rg = wave & 1;          // row group: 16 rows
    const int cg = wave >> 1;         // col group: 64 cols (4 nt)
    const int i0 = blockIdx.x * 32;

    const float* aptr = alpha + (size_t)(i0 + rg * 16 + lo) * NROW + q8;

    // staging: linear LDS dest (gload_lds), source chunk XOR'd with row&7
    const int srow = lane >> 3;
    const int swz = ((lane & 7) ^ srow) * 8;

    // fragment read offsets (shorts), same XOR on read side
    const int bx0 = (quad ^ (lo & 7)) * 8;
    const int bx1 = ((4 + quad) ^ (lo & 7)) * 8;
    int off0[4], off1[4];
#pragma unroll
    for (int nt = 0; nt < 4; ++nt) {
        int rb = (cg * 64 + nt * 16 + lo) * 64;
        off0[nt] = rb + bx0;
        off1[nt] = rb + bx1;
    }

    f32x4 acc[4] = {};
    f32x4 aA[4], aB[4], aC[4], aD[4];   // A prefetch sets, static idx only

#define STAGE(buf, kt)                                                        \
    {                                                                         \
        const short* gtile = whbT + (size_t)(kt) * 16384;                     \
        _Pragma("unroll")                                                     \
        for (int s = 0; s < 4; ++s)                                           \
            gload_lds16(gtile + ((wave * 4 + s) * 8 + srow) * 64 + swz,       \
                        &Bs[buf][(wave * 4 + s) * 512]);                      \
    }

#define ALOAD(set, kt)                                                        \
    {                                                                         \
        const float* ap = aptr + (size_t)(kt) * 64;                           \
        asm volatile("global_load_dwordx4 %0, %4, off\n\t"                    \
                     "global_load_dwordx4 %1, %4, off offset:16\n\t"          \
                     "global_load_dwordx4 %2, %4, off offset:128\n\t"         \
                     "global_load_dwordx4 %3, %4, off offset:144"             \
                     : "=&v"(aA[set]), "=&v"(aB[set]),                        \
                       "=&v"(aC[set]), "=&v"(aD[set])                         \
                     : "v"(ap));                                              \
    }

#define CONSUME(c)                                                            \
    {                                                                         \
        bf16x8 af0, af1;                                                      \
        af0[0] = f2bf(aA[c][0]); af0[1] = f2bf(aA[c][1]);                     \
        af0[2] = f2bf(aA[c][2]); af0[3] = f2bf(aA[c][3]);                     \
        af0[4] = f2bf(aB[c][0]); af0[5] = f2bf(aB[c][1]);                     \
        af0[6] = f2bf(aB[c][2]); af0[7] = f2bf(aB[c][3]);                     \
        af1[0] = f2bf(aC[c][0]); af1[1] = f2bf(aC[c][1]);                     \
        af1[2] = f2bf(aC[c][2]); af1[3] = f2bf(aC[c][3]);                     \
        af1[4] = f2bf(aD[c][0]); af1[5] = f2bf(aD[c][1]);                     \
        af1[6] = f2bf(aD[c][2]); af1[7] = f2bf(aD[c][3]);                     \
        _Pragma("unroll")                                                     \
        for (int nt = 0; nt < 4; ++nt) {                                      \
            bf16x8 b0 = *(const bf16x8*)&Bs[c][off0[nt]];                     \
            acc[nt] = __builtin_amdgcn_mfma_f32_16x16x32_bf16(af0, b0,        \
                                                          acc[nt], 0, 0, 0);  \
            bf16x8 b1 = *(const bf16x8*)&Bs[c][off1[nt]];                     \
            acc[nt] = __builtin_amdgcn_mfma_f32_16x16x32_bf16(af1, b1,        \
                                                          acc[nt], 0, 0, 0);  \
        }                                                                     \
    }

#define KSTEP_FULL(kt, c)                                                     \
    {                                                                         \
        STAGE(((c) + 2) & 3, (kt) + 2);                                       \
        ALOAD(((c) + 2) & 3, (kt) + 2);                                       \
        asm volatile("s_waitcnt vmcnt(16)" ::: "memory");                     \
        __builtin_amdgcn_s_barrier();                                         \
        __builtin_amdgcn_sched_barrier(0);                                    \
        CONSUME(c)                                                            \
    }

    // prologue: issue tiles 0 and 1 (stage depth 2, A depth 2)
    STAGE(0, 0); ALOAD(0, 0);
    STAGE(1, 1); ALOAD(1, 1);

#pragma unroll 1
    for (int base = 0; base < 124; base += 4) {
        KSTEP_FULL(base + 0, 0)
        KSTEP_FULL(base + 1, 1)
        KSTEP_FULL(base + 2, 2)
        KSTEP_FULL(base + 3, 3)
    }
    KSTEP_FULL(124, 0)
    KSTEP_FULL(125, 1)
    // kt = 126: nothing left to issue; S(126)/A(126) are 8 ops back
    asm volatile("s_waitcnt vmcnt(8)" ::: "memory");
    __builtin_amdgcn_s_barrier();
    __builtin_amdgcn_sched_barrier(0);
    CONSUME(2)
    // kt = 127: drain
    asm volatile("s_waitcnt vmcnt(0)" ::: "memory");
    __builtin_amdgcn_s_barrier();
    __builtin_amdgcn_sched_barrier(0);
    CONSUME(3)

#undef STAGE
#undef ALOAD
#undef CONSUME
#undef KSTEP_FULL

    // C/D layout: col = lane&15, row = quad*4 + reg. elu fused.
    const int ccb = cg * 64 + lo;
#pragma unroll
    for (int nt = 0; nt < 4; ++nt) {
#pragma unroll
        for (int c = 0; c < 4; ++c) {
            const int rr = i0 + rg * 16 + quad * 4 + c;
            float v = acc[nt][c];
            v = v > 0.f ? v : __expf(v) - 1.f;
            out0[(size_t)rr * DIM + ccb + nt * 16] = v;
        }
    }
}

extern "C" void kernel_launch(void* const* d_in, const int* in_sizes, int n_in,
                              void* d_out, int out_size, void* d_ws, size_t ws_size,
                              hipStream_t stream) {
    const float* h = (const float*)d_in[0];
    const int* adj = (const int*)d_in[1];
    const float* W = (const float*)d_in[2];
    const float* a = (const float*)d_in[3];
    float* out0 = (float*)d_out;                        // elu(h_prime) [8192,256]
    float* alpha = out0 + (size_t)NROW * DIM;           // alpha [8192,8192]

    char* ws = (char*)d_ws;
    float* f = (float*)ws;                              // 32 KB
    short* whbT = (short*)(ws + 32768);                 // 4 MB bf16, K-tiled

    hipMemsetAsync(f, 0, NROW * sizeof(float), stream);
    k1_whgemm<<<dim3(NROW / 64, DIM / 64), 256, 0, stream>>>(h, W, a, whbT, f);
    k3d_alpha<<<dim3(NROW), 256, 0, stream>>>(adj, f, alpha);
    k4e_gemm<<<dim3(NROW / 32), 512, 0, stream>>>(alpha, whbT, out0);
}

// Round 5
// 607.704 us; speedup vs baseline: 1.0880x; 1.0512x over previous
//
#include <hip/hip_runtime.h>
#include <hip/hip_bf16.h>

#define NROW 8192
#define DIM 256

typedef short bf16x8 __attribute__((ext_vector_type(8)));
typedef float f32x4 __attribute__((ext_vector_type(4)));

__device__ __forceinline__ short f2bf(float x) {
    return __builtin_bit_cast(short, __float2bfloat16(x));
}

__device__ __forceinline__ void gload_lds16(const void* g, void* l) {
    __builtin_amdgcn_global_load_lds(
        (const __attribute__((address_space(1))) unsigned int*)g,
        (__attribute__((address_space(3))) unsigned int*)l, 16, 0, 0);
}

// ---------------------------------------------------------------------------
// k1: Wh = h @ W (fp32 accum). Epilogue: f[j] += Wh[j][:] . a  (atomic partial
// per 64-col block) and whbT in K-TILED layout for k4's global_load_lds:
//   whbT[((k>>6)*256 + n)*64 + (k&63)] = bf16(Wh[k][n])
// grid (128, 4), block 256
// ---------------------------------------------------------------------------
__global__ __launch_bounds__(256) void k1_whgemm(
    const float* __restrict__ h, const float* __restrict__ W,
    const float* __restrict__ a, short* __restrict__ whbT,
    float* __restrict__ f)
{
    __shared__ float hs[64][65];
    __shared__ float wsm[64][65];
    const int tid = threadIdx.x;
    const int tx = tid & 15, ty = tid >> 4;
    const int i0 = blockIdx.x * 64;
    const int n0 = blockIdx.y * 64;

    float acc[4][4];
#pragma unroll
    for (int u = 0; u < 4; ++u)
#pragma unroll
        for (int v = 0; v < 4; ++v) acc[u][v] = 0.f;

    for (int kb = 0; kb < DIM; kb += 64) {
#pragma unroll
        for (int rr = 0; rr < 4; ++rr) {
            int row = rr * 16 + ty;
            *(float4*)&hs[row][tx * 4] =
                *(const float4*)&h[(size_t)(i0 + row) * DIM + kb + tx * 4];
            *(float4*)&wsm[row][tx * 4] =
                *(const float4*)&W[(size_t)(kb + row) * DIM + n0 + tx * 4];
        }
        __syncthreads();
#pragma unroll 8
        for (int kk = 0; kk < 64; ++kk) {
            float av[4], bv[4];
#pragma unroll
            for (int u = 0; u < 4; ++u) av[u] = hs[ty * 4 + u][kk];
#pragma unroll
            for (int v = 0; v < 4; ++v) bv[v] = wsm[kk][tx * 4 + v];
#pragma unroll
            for (int u = 0; u < 4; ++u)
#pragma unroll
                for (int v = 0; v < 4; ++v) acc[u][v] += av[u] * bv[v];
        }
        __syncthreads();
    }

#pragma unroll
    for (int u = 0; u < 4; ++u)
#pragma unroll
        for (int v = 0; v < 4; ++v) hs[ty * 4 + u][tx * 4 + v] = acc[u][v];
    __syncthreads();

    {
        int r = tid >> 2, q = tid & 3;
        float s = 0.f;
#pragma unroll
        for (int c = 0; c < 16; ++c) s += hs[r][q * 16 + c] * a[n0 + q * 16 + c];
        s += __shfl_xor(s, 1);
        s += __shfl_xor(s, 2);
        if (q == 0) atomicAdd(&f[i0 + r], s);
    }

    {
        int n = tid >> 2, q = tid & 3;
        union { short s[16]; int4 i4[2]; } pk;
#pragma unroll
        for (int b = 0; b < 4; ++b)
#pragma unroll
            for (int c = 0; c < 4; ++c)
                pk.s[b * 4 + c] = f2bf(hs[q * 16 + b * 4 + c][n]);
        size_t base = ((size_t)(i0 >> 6) * 256 + n0 + n) * 64 + q * 16;
        *(int4*)&whbT[base] = pk.i4[0];
        *(int4*)&whbT[base + 8] = pk.i4[1];
    }
}

// ---------------------------------------------------------------------------
// k3d: one block per row i. Burst-issue all 16 loads, exp in place, reduce,
// scale, float4 stores. grid 8192, block 256
// ---------------------------------------------------------------------------
__global__ __launch_bounds__(256) void k3d_alpha(
    const int* __restrict__ adj, const float* __restrict__ f,
    float* __restrict__ alpha)
{
    const int i = blockIdx.x;
    const int tid = threadIdx.x;
    const float fi = f[i];
    const int* row = adj + (size_t)i * NROW;

    int4 av[8];
    float4 fv[8];
#pragma unroll
    for (int it = 0; it < 8; ++it)
        av[it] = *(const int4*)&row[it * 1024 + tid * 4];
#pragma unroll
    for (int it = 0; it < 8; ++it)
        fv[it] = *(const float4*)&f[it * 1024 + tid * 4];

    float sum = 0.f;
#pragma unroll
    for (int it = 0; it < 8; ++it) {
        float x0 = fi + fv[it].x, x1 = fi + fv[it].y;
        float x2 = fi + fv[it].z, x3 = fi + fv[it].w;
        float4 t;
        t.x = av[it].x > 0 ? __expf(fmaxf(x0, 0.2f * x0)) : 0.f;
        t.y = av[it].y > 0 ? __expf(fmaxf(x1, 0.2f * x1)) : 0.f;
        t.z = av[it].z > 0 ? __expf(fmaxf(x2, 0.2f * x2)) : 0.f;
        t.w = av[it].w > 0 ? __expf(fmaxf(x3, 0.2f * x3)) : 0.f;
        fv[it] = t;
        sum += t.x + t.y + t.z + t.w;
    }

#pragma unroll
    for (int off = 32; off > 0; off >>= 1) sum += __shfl_xor(sum, off);
    __shared__ float red[4];
    if ((tid & 63) == 0) red[tid >> 6] = sum;
    __syncthreads();
    const float inv = 1.f / (red[0] + red[1] + red[2] + red[3]);

    float* arow = alpha + (size_t)i * NROW;
#pragma unroll
    for (int it = 0; it < 8; ++it) {
        float4 t = fv[it];
        float4 o = {t.x * inv, t.y * inv, t.z * inv, t.w * inv};
        *(float4*)&arow[it * 1024 + tid * 4] = o;
    }
}

// ---------------------------------------------------------------------------
// k4g: out0 = elu(alpha @ Wh), COLUMN-SPLIT blocks: 128 rows x 64 cols,
// full K per block -> no atomics, elu fused. grid 256 (1/CU), 512 threads
// = 8 waves, wave = row-group (16 rows), 4 nt of 16 cols. No A-duplication.
// whbT per block = 1 MB (its 64 cols) -> 256 MB aggregate, L2-resident.
// XCD-pinned decode: the 4 col-splits of each row-group share an XCD so
// their alpha stream dedups in that XCD's L2.
// Depth-2 counted-vmcnt pipeline (proven in k4e): 4 x 8 KB LDS buffers,
// 5 vmem ops/iter (1 gload_lds + 4 asm A-loads), vmcnt(10)/(5)/(0).
// ---------------------------------------------------------------------------
__global__ __launch_bounds__(512) void k4g_gemm(
    const float* __restrict__ alpha, const short* __restrict__ whbT,
    float* __restrict__ out0)
{
    __shared__ __align__(16) short Bs[4][4096];   // 4 x 8 KB = 32 KB

    const int tid = threadIdx.x;
    const int wave = tid >> 6;
    const int lane = tid & 63;
    const int lo = lane & 15;
    const int quad = lane >> 4;
    const int q8 = quad * 8;

    // XCD-pinned block decode: bid&7 = XCD (dispatch round-robin), so the
    // 4 col-splits of row-block rb land on the same XCD's L2.
    const int bid = blockIdx.x;
    const int xcd = bid & 7;
    const int slot = bid >> 3;            // 0..31
    const int rb = xcd * 8 + (slot & 7);  // 0..63
    const int cs = slot >> 3;             // 0..3
    const int i0 = rb * 128;
    const int n0 = cs * 64;

    const float* aptr = alpha + (size_t)(i0 + wave * 16 + lo) * NROW + q8;

    // staging: thread tid stages 16 B of the [64 n][64 k] tile.
    // n_local = tid>>3, chunk = tid&7, source chunk XOR'd with n&7
    // (involution); LDS dest linear tid*16 B (wave-uniform base + lane*16).
    const int n_local = tid >> 3;
    const int schunk = ((tid & 7) ^ (n_local & 7)) * 8;   // shorts

    // fragment read offsets (shorts), same XOR on read side (n&7 == lo&7)
    const int bx0 = (quad ^ (lo & 7)) * 8;
    const int bx1 = ((4 + quad) ^ (lo & 7)) * 8;
    int off0[4], off1[4];
#pragma unroll
    for (int nt = 0; nt < 4; ++nt) {
        int rbase = (nt * 16 + lo) * 64;
        off0[nt] = rbase + bx0;
        off1[nt] = rbase + bx1;
    }

    f32x4 acc[4] = {};
    f32x4 aA[4], aB[4], aC[4], aD[4];   // A prefetch sets, static idx only

#define STAGE(buf, kt)                                                        \
    {                                                                         \
        const short* gsrc = whbT + (size_t)(kt) * 16384 +                     \
                            (n0 + n_local) * 64 + schunk;                     \
        gload_lds16(gsrc, &Bs[buf][tid * 8]);                                 \
    }

#define ALOAD(set, kt)                                                        \
    {                                                                         \
        const float* ap = aptr + (size_t)(kt) * 64;                           \
        asm volatile("global_load_dwordx4 %0, %4, off\n\t"                    \
                     "global_load_dwordx4 %1, %4, off offset:16\n\t"          \
                     "global_load_dwordx4 %2, %4, off offset:128\n\t"         \
                     "global_load_dwordx4 %3, %4, off offset:144"             \
                     : "=&v"(aA[set]), "=&v"(aB[set]),                        \
                       "=&v"(aC[set]), "=&v"(aD[set])                         \
                     : "v"(ap));                                              \
    }

#define CONSUME(c)                                                            \
    {                                                                         \
        bf16x8 af0, af1;                                                      \
        af0[0] = f2bf(aA[c][0]); af0[1] = f2bf(aA[c][1]);                     \
        af0[2] = f2bf(aA[c][2]); af0[3] = f2bf(aA[c][3]);                     \
        af0[4] = f2bf(aB[c][0]); af0[5] = f2bf(aB[c][1]);                     \
        af0[6] = f2bf(aB[c][2]); af0[7] = f2bf(aB[c][3]);                     \
        af1[0] = f2bf(aC[c][0]); af1[1] = f2bf(aC[c][1]);                     \
        af1[2] = f2bf(aC[c][2]); af1[3] = f2bf(aC[c][3]);                     \
        af1[4] = f2bf(aD[c][0]); af1[5] = f2bf(aD[c][1]);                     \
        af1[6] = f2bf(aD[c][2]); af1[7] = f2bf(aD[c][3]);                     \
        _Pragma("unroll")                                                     \
        for (int nt = 0; nt < 4; ++nt) {                                      \
            bf16x8 b0 = *(const bf16x8*)&Bs[c][off0[nt]];                     \
            acc[nt] = __builtin_amdgcn_mfma_f32_16x16x32_bf16(af0, b0,        \
                                                          acc[nt], 0, 0, 0);  \
            bf16x8 b1 = *(const bf16x8*)&Bs[c][off1[nt]];                     \
            acc[nt] = __builtin_amdgcn_mfma_f32_16x16x32_bf16(af1, b1,        \
                                                          acc[nt], 0, 0, 0);  \
        }                                                                     \
    }

#define KSTEP(kt, c, DO, N)                                                   \
    {                                                                         \
        if (DO) { STAGE(((c) + 2) & 3, (kt) + 2); ALOAD(((c) + 2) & 3,        \
                                                        (kt) + 2); }          \
        asm volatile("s_waitcnt vmcnt(" #N ")" ::: "memory");                 \
        __builtin_amdgcn_s_barrier();                                         \
        __builtin_amdgcn_sched_barrier(0);                                    \
        CONSUME(c)                                                            \
    }

    // prologue: issue tiles 0 and 1 (depth 2) = 10 vmem ops per wave
    STAGE(0, 0); ALOAD(0, 0);
    STAGE(1, 1); ALOAD(1, 1);

#pragma unroll 1
    for (int base = 0; base < 124; base += 4) {
        KSTEP(base + 0, 0, true, 10)
        KSTEP(base + 1, 1, true, 10)
        KSTEP(base + 2, 2, true, 10)
        KSTEP(base + 3, 3, true, 10)
    }
    KSTEP(124, 0, true, 10)    // stages tile 126
    KSTEP(125, 1, true, 10)    // stages tile 127
    KSTEP(126, 2, false, 5)    // outstanding 10 -> drain tile 126
    KSTEP(127, 3, false, 0)    // drain all

#undef STAGE
#undef ALOAD
#undef CONSUME
#undef KSTEP

    // C/D layout: col = lane&15, row = quad*4 + reg. elu fused, plain store.
    const int ccb = n0 + lo;
#pragma unroll
    for (int nt = 0; nt < 4; ++nt) {
#pragma unroll
        for (int c = 0; c < 4; ++c) {
            const int rr = i0 + wave * 16 + quad * 4 + c;
            float v = acc[nt][c];
            v = v > 0.f ? v : __expf(v) - 1.f;
            out0[(size_t)rr * DIM + ccb + nt * 16] = v;
        }
    }
}

extern "C" void kernel_launch(void* const* d_in, const int* in_sizes, int n_in,
                              void* d_out, int out_size, void* d_ws, size_t ws_size,
                              hipStream_t stream) {
    const float* h = (const float*)d_in[0];
    const int* adj = (const int*)d_in[1];
    const float* W = (const float*)d_in[2];
    const float* a = (const float*)d_in[3];
    float* out0 = (float*)d_out;                        // elu(h_prime) [8192,256]
    float* alpha = out0 + (size_t)NROW * DIM;           // alpha [8192,8192]

    char* ws = (char*)d_ws;
    float* f = (float*)ws;                              // 32 KB
    short* whbT = (short*)(ws + 32768);                 // 4 MB bf16, K-tiled

    hipMemsetAsync(f, 0, NROW * sizeof(float), stream);
    k1_whgemm<<<dim3(NROW / 64, DIM / 64), 256, 0, stream>>>(h, W, a, whbT, f);
    k3d_alpha<<<dim3(NROW), 256, 0, stream>>>(adj, f, alpha);
    k4g_gemm<<<dim3(256), 512, 0, stream>>>(alpha, whbT, out0);
}